// Round 7
// baseline (75.622 us; speedup 1.0000x reference)
//
#include <hip/hip_runtime.h>
#include <stdint.h>

#define SEQ 2048
#define BATCH 4
#define EMB 512
#define MTOT (BATCH * SEQ)   // 8192 rows
#define WIN 16
#define WINDOW 33            // 2*WIN+1

typedef uint32_t u32;
typedef unsigned short u16;
typedef __attribute__((ext_vector_type(8))) __bf16 bf16x8;
typedef __attribute__((ext_vector_type(4))) float f32x4;
typedef __attribute__((ext_vector_type(4))) u16 u16x4;
typedef __attribute__((ext_vector_type(8))) u16 u16x8;

__device__ __forceinline__ u16 f2bf(float f) {  // RNE f32->bf16
  u32 u = __builtin_bit_cast(u32, f);
  u = (u + 0x7fffu + ((u >> 16) & 1u)) >> 16;
  return (u16)u;
}
__device__ __forceinline__ float bf2f(u16 v) {
  return __builtin_bit_cast(float, (u32)v << 16);
}
__device__ __forceinline__ void gload16(void* lds, const void* g) {
  __builtin_amdgcn_global_load_lds((const __attribute__((address_space(1))) u32*)g,
                                   (__attribute__((address_space(3))) u32*)lds, 16, 0, 0);
}
// Explicit drain of LDS-DMA (vm) + ds ops (lgkm) before a publishing barrier.
__device__ __forceinline__ void drain_stage() {
  asm volatile("s_waitcnt vmcnt(0) lgkmcnt(0)" ::: "memory");
}

// ============ launch 1: Wv/Wo casts || fp32 atmat (reg-prefetched) || cvec || econst+bvb ==
// blocks [0,256): Wv cast | [256,512): Wo cast | [512,768): atmat 32x32 tiles |
// [768,776): cvec | 776: econst + bvb
__global__ void __launch_bounds__(256) prep1(
    const float* __restrict__ Wq, const float* __restrict__ Wk,
    const float* __restrict__ Wv, const float* __restrict__ Wo,
    const float* __restrict__ bq, const float* __restrict__ bk, const float* __restrict__ bv,
    u16* __restrict__ Wvb, u16* __restrict__ Wob, u16* __restrict__ Atm,
    u16* __restrict__ bvb, float* __restrict__ cvec, float* __restrict__ econst) {
  __shared__ float sm[2][32][36];   // atmat tiles (float4-aligned, conflict-free)
  int b = blockIdx.x, t = threadIdx.x;
  if (b < 512) {                          // ---- Wv / Wo cast (float4/thread)
    const float* S = (b < 256) ? Wv : Wo;
    u16* D = (b < 256) ? Wvb : Wob;
    int i = ((b & 255) * 256 + t) * 4;
    float4 v = *reinterpret_cast<const float4*>(S + i);
    u16x4 o; o.x = f2bf(v.x); o.y = f2bf(v.y); o.z = f2bf(v.z); o.w = f2bf(v.w);
    *reinterpret_cast<u16x4*>(D + i) = o;
  } else if (b < 768) {                   // ---- At[n][k] = sum_d Wk[d][n]*Wq[d][k]
    int bid = b - 512;
    int k0 = (bid & 15) * 32, n0 = (bid >> 4) * 32;
    int lr = t >> 5, lc = t & 31;         // lr: row-group, lc: col
    float acc[4] = {0.f, 0.f, 0.f, 0.f};
    float rK[4], rQ[4];
#pragma unroll
    for (int rr = 0; rr < 4; ++rr) {      // prologue loads (d0 = 0)
      rK[rr] = Wk[(size_t)(rr * 8 + lr) * EMB + n0 + lc];
      rQ[rr] = Wq[(size_t)(rr * 8 + lr) * EMB + k0 + lc];
    }
    for (int d0 = 0; d0 < EMB; d0 += 32) {
      __syncthreads();                    // prior compute reads done
#pragma unroll
      for (int rr = 0; rr < 4; ++rr) {
        sm[0][rr * 8 + lr][lc] = rK[rr];
        sm[1][rr * 8 + lr][lc] = rQ[rr];
      }
      __syncthreads();
      if (d0 + 32 < EMB) {                // prefetch next stripe during compute
#pragma unroll
        for (int rr = 0; rr < 4; ++rr) {
          rK[rr] = Wk[(size_t)(d0 + 32 + rr * 8 + lr) * EMB + n0 + lc];
          rQ[rr] = Wq[(size_t)(d0 + 32 + rr * 8 + lr) * EMB + k0 + lc];
        }
      }
#pragma unroll 8
      for (int d = 0; d < 32; ++d) {
        float q = sm[1][d][lc];                                   // broadcast per lane
        float4 kv = *reinterpret_cast<const float4*>(&sm[0][d][lr * 4]);  // b128 broadcast
        acc[0] += kv.x * q; acc[1] += kv.y * q; acc[2] += kv.z * q; acc[3] += kv.w * q;
      }
    }
#pragma unroll
    for (int i = 0; i < 4; ++i)
      Atm[(size_t)(n0 + lr * 4 + i) * EMB + k0 + lc] = f2bf(acc[i]);
  } else if (b < 776) {                   // ---- cvec[i] = sum_d Wq[d][i]*bk[d]+Wk[d][i]*bq[d]
    float* sh = &sm[0][0][0];
    int cb = b - 768;
    int ii = t >> 2, di = t & 3;
    int i = cb * 64 + ii;
    float s = 0.f;
    for (int d = di * 128; d < di * 128 + 128; ++d)
      s += Wq[(size_t)d * EMB + i] * bk[d] + Wk[(size_t)d * EMB + i] * bq[d];
    sh[t] = s;
    __syncthreads();
    if (di == 0) cvec[i] = sh[t] + sh[t + 1] + sh[t + 2] + sh[t + 3];
  } else {                                // ---- econst = bq.bk ; bvb cast
    float* sh = &sm[0][0][0];
    bvb[t] = f2bf(bv[t]);
    bvb[t + 256] = f2bf(bv[t + 256]);
    float s = bq[t] * bk[t] + bq[t + 256] * bk[t + 256];
    sh[t] = s;
    __syncthreads();
    for (int st = 128; st > 0; st >>= 1) {
      if (t < st) sh[t] += sh[t + st];
      __syncthreads();
    }
    if (t == 0) *econst = sh[0];
  }
}

// ============ launch 2: E rowdot (by<4) + V GEMM (by>=4); BK=64, 2-phase double-buffer ====
// A self-staged from fp32 x (issue-early regs, write-late); B via global_load_lds DMA.
__global__ void __launch_bounds__(256) gemm_ev2(
    const float* __restrict__ x, const u16* __restrict__ Atm, const u16* __restrict__ Wvb,
    const float* __restrict__ bv, const float* __restrict__ cvec,
    float* __restrict__ e_part, u16* __restrict__ Vb) {
  __shared__ u16 AtL[2][128 * 64];       // 16 KB each
  __shared__ u16 BtL[2][128 * 64];       // 64 KB total -> 2 blocks/CU
  int b = blockIdx.x;                    // 512 blocks
  int wg = ((b & 7) << 6) + (b >> 3);    // XCD-chunked swizzle (bijective: 512 = 8*64)
  int by = wg & 7, bx = wg >> 3;
  bool isE = by < 4;
  int t = threadIdx.x;
  int wave = t >> 6, lane = t & 63;
  int wr = wave >> 1, wc = wave & 1;
  int fr = lane & 15, fq = lane >> 4;
  int m0 = bx * 128;
  int n0 = (by & 3) * 128;
  const u16* Bm = isE ? Atm : Wvb;

  float4 rA[8];
  // ---- staging helpers (BK=64) ----
  auto stageB = [&](int buf, int kt) {   // 128x64 bf16 via DMA: 4 gloads/thread
    int kb = kt * 64;
#pragma unroll
    for (int it = 0; it < 4; ++it) {
      int chunk = t + it * 256;
      int row = chunk >> 3, col8 = (chunk & 7) * 8;
      gload16(&BtL[buf][(size_t)(wave * 64 + it * 256) * 8],
              Bm + (size_t)(n0 + row) * EMB + kb + col8);
    }
  };
  auto loadA = [&](int kt) {             // 128x64 fp32 -> regs: 8 float4/thread
    int kb = kt * 64;
#pragma unroll
    for (int p = 0; p < 8; ++p) {
      int fchunk = t + p * 256;
      int row = fchunk >> 4, c4 = (fchunk & 15) * 4;
      rA[p] = *reinterpret_cast<const float4*>(x + (size_t)(m0 + row) * EMB + kb + c4);
    }
  };
  auto writeA = [&](int buf) {           // cast + ds_write
#pragma unroll
    for (int p = 0; p < 8; ++p) {
      int fchunk = t + p * 256;
      int row = fchunk >> 4, c4 = (fchunk & 15) * 4;
      u16x4 o; o.x = f2bf(rA[p].x); o.y = f2bf(rA[p].y); o.z = f2bf(rA[p].z); o.w = f2bf(rA[p].w);
      *reinterpret_cast<u16x4*>(&AtL[buf][row * 64 + c4]) = o;
    }
  };

  f32x4 acc[4][4] = {};
  // prologue: stage tile 0 into buf 0
  stageB(0, 0);
  loadA(0);
  drain_stage();
  writeA(0);
  drain_stage();
  __syncthreads();
  int cur = 0;
  for (int kt = 0; kt < 8; ++kt) {
    int nxt = cur ^ 1;
    if (kt < 7) {                        // issue next-tile loads BEFORE compute
      stageB(nxt, kt + 1);
      loadA(kt + 1);
    }
    bf16x8 af[4][2], bfv[4][2];
#pragma unroll
    for (int m = 0; m < 4; ++m)
#pragma unroll
      for (int kk = 0; kk < 2; ++kk)
        af[m][kk] = *reinterpret_cast<const bf16x8*>(
            &AtL[cur][(wr * 64 + m * 16 + fr) * 64 + kk * 32 + fq * 8]);
#pragma unroll
    for (int n = 0; n < 4; ++n)
#pragma unroll
      for (int kk = 0; kk < 2; ++kk)
        bfv[n][kk] = *reinterpret_cast<const bf16x8*>(
            &BtL[cur][(wc * 64 + n * 16 + fr) * 64 + kk * 32 + fq * 8]);
#pragma unroll
    for (int m = 0; m < 4; ++m)
#pragma unroll
      for (int n = 0; n < 4; ++n) {
        acc[m][n] = __builtin_amdgcn_mfma_f32_16x16x32_bf16(af[m][0], bfv[n][0], acc[m][n], 0, 0, 0);
        acc[m][n] = __builtin_amdgcn_mfma_f32_16x16x32_bf16(af[m][1], bfv[n][1], acc[m][n], 0, 0, 0);
      }
    if (kt < 7) {
      drain_stage();                     // A-regs landed + B-DMA landed
      writeA(nxt);
    }
    drain_stage();                       // ds_writes + DMA drained before publish
    __syncthreads();
    cur = nxt;
  }

  if (isE) {
    float cv[4];
#pragma unroll
    for (int n = 0; n < 4; ++n) cv[n] = cvec[n0 + wc * 64 + n * 16 + fr];
#pragma unroll
    for (int m = 0; m < 4; ++m) {
#pragma unroll
      for (int r = 0; r < 4; ++r) {
        int row = m0 + wr * 64 + m * 16 + fq * 4 + r;
        float p = 0.f;
#pragma unroll
        for (int n = 0; n < 4; ++n) {
          int col = n0 + wc * 64 + n * 16 + fr;
          p += (acc[m][n][r] + cv[n]) * x[(size_t)row * EMB + col];
        }
        p += __shfl_xor(p, 1);
        p += __shfl_xor(p, 2);
        p += __shfl_xor(p, 4);
        p += __shfl_xor(p, 8);
        if (fr == 0) e_part[(size_t)(by * 2 + wc) * MTOT + row] = p;
      }
    }
  } else {
    float bvv[4];
#pragma unroll
    for (int n = 0; n < 4; ++n) bvv[n] = bv[n0 + wc * 64 + n * 16 + fr];
#pragma unroll
    for (int m = 0; m < 4; ++m)
#pragma unroll
      for (int n = 0; n < 4; ++n) {
        int col = n0 + wc * 64 + n * 16 + fr;
#pragma unroll
        for (int r = 0; r < 4; ++r) {
          int row = m0 + wr * 64 + m * 16 + fq * 4 + r;
          Vb[(size_t)row * EMB + col] = f2bf(acc[m][n][r] + bvv[n]);
        }
      }
  }
}

// ============ launch 3: window softmax + weighted V sum -> ao (bf16) ============
// V staged via plain loads + ds_write_b128 (no LDS-DMA: divergent pad source).
__global__ void __launch_bounds__(256) window2(
    const u16* __restrict__ Vb, const float* __restrict__ e_part,
    const float* __restrict__ econst_p, const u16* __restrict__ bvb,
    u16* __restrict__ ao) {
  __shared__ u16 Vt[48 * EMB];      // 48 rows x 512 bf16 = 49152 B
  __shared__ float eloc[48];
  __shared__ float w[16][WINDOW];
  int b = blockIdx.x;                    // 512 blocks
  int swz = ((b & 7) << 6) + (b >> 3);   // XCD-chunked: neighbor s0 share V halo in L2
  int bb = swz >> 7;
  int s0 = (swz & 127) * 16;
  int t = threadIdx.x;
  // ---- stage 48 V rows: issue all 12 loads, then 12 ds_writes (reg-staged) ----
  u16x8 stg[12];
#pragma unroll
  for (int i = 0; i < 12; ++i) {
    int chunk = t + i * 256;
    int row = chunk >> 6;
    int c8 = (chunk & 63) * 8;
    int n = s0 + row - WIN;
    const u16* src = (n >= 0 && n < SEQ) ? (Vb + (size_t)(bb * SEQ + n) * EMB + c8)
                                         : (bvb + c8);
    stg[i] = *reinterpret_cast<const u16x8*>(src);
  }
#pragma unroll
  for (int i = 0; i < 12; ++i) {
    int chunk = t + i * 256;
    int row = chunk >> 6;
    int c8 = (chunk & 63) * 8;
    *reinterpret_cast<u16x8*>(&Vt[(size_t)row * EMB + c8]) = stg[i];
  }
  const float scale = 0.044194173824159216f;  // 1/sqrt(512)
  float ec = *econst_p;
  if (t < 48) {                          // scores for positions s0-16 .. s0+31
    int n = s0 + t - WIN;
    float raw = 0.f;
    if (n >= 0 && n < SEQ) {
      size_t idx = (size_t)bb * SEQ + n;
#pragma unroll
      for (int p = 0; p < 8; ++p) raw += e_part[(size_t)p * MTOT + idx];
    }
    eloc[t] = scale * (raw + ec);        // pad: raw==0 -> scale*bq.bk, exact
  }
  __syncthreads();
  if (t < 16) {
    float ev[WINDOW];
    float mx = -1e30f;
#pragma unroll
    for (int j = 0; j < WINDOW; ++j) { ev[j] = eloc[t + j]; mx = fmaxf(mx, ev[j]); }
    float sum = 0.f;
#pragma unroll
    for (int j = 0; j < WINDOW; ++j) { float ex = __expf(ev[j] - mx); ev[j] = ex; sum += ex; }
    float inv = 1.f / sum;
#pragma unroll
    for (int j = 0; j < WINDOW; ++j) w[t][j] = ev[j] * inv;
  }
  __syncthreads();
  // each thread: 8 columns x 4 query rows; read each V row once (b128)
  int cg = t & 63;
  int slg = t >> 6;                      // query group of 4
  int d0 = cg * 8;
  float oacc[4][8] = {};
  for (int ri = 0; ri < 36; ++ri) {
    int r = slg * 4 + ri;
    u16x8 v = *reinterpret_cast<const u16x8*>(&Vt[(size_t)r * EMB + d0]);
    float vf[8];
#pragma unroll
    for (int c = 0; c < 8; ++c) vf[c] = bf2f(v[c]);
#pragma unroll
    for (int q = 0; q < 4; ++q) {
      int j = ri - q;                    // compile-time per (ri,q)
      if (j >= 0 && j < WINDOW) {
        float wt = w[slg * 4 + q][j];
#pragma unroll
        for (int c = 0; c < 8; ++c) oacc[q][c] += wt * vf[c];
      }
    }
  }
#pragma unroll
  for (int q = 0; q < 4; ++q) {
    u16x8 o;
#pragma unroll
    for (int c = 0; c < 8; ++c) o[c] = f2bf(oacc[q][c]);
    *reinterpret_cast<u16x8*>(&ao[(size_t)(bb * SEQ + s0 + slg * 4 + q) * EMB + d0]) = o;
  }
}

// ============ launch 4: out = ao @ Wo^T + bo; 64x128 tiles, BK=64, 2-phase dbuf ==========
__global__ void __launch_bounds__(256) ogemm(
    const u16* __restrict__ ao, const u16* __restrict__ Wob,
    const float* __restrict__ bo, float* __restrict__ out) {
  __shared__ u16 At2[2][64 * 64];   // 8 KB each
  __shared__ u16 Bt2[2][128 * 64];  // 16 KB each -> 48 KB total
  int b = blockIdx.x;                    // 512 blocks
  int wg = ((b & 7) << 6) + (b >> 3);    // XCD-chunked swizzle
  int bx = wg >> 2, by = wg & 3;
  int t = threadIdx.x;
  int wave = t >> 6, lane = t & 63;
  int wr = wave >> 1, wc = wave & 1;
  int fr = lane & 15, fq = lane >> 4;
  int m0 = bx * 64, n0 = by * 128;

  auto stage = [&](int buf, int kt) {
    int kb = kt * 64;
#pragma unroll
    for (int it = 0; it < 2; ++it) {     // A: 64x64 bf16 = 2 gloads/thread
      int chunk = t + it * 256;
      int row = chunk >> 3, col8 = (chunk & 7) * 8;
      gload16(&At2[buf][(size_t)(wave * 64 + it * 256) * 8],
              ao + (size_t)(m0 + row) * EMB + kb + col8);
    }
#pragma unroll
    for (int it = 0; it < 4; ++it) {     // B: 128x64 bf16 = 4 gloads/thread
      int chunk = t + it * 256;
      int row = chunk >> 3, col8 = (chunk & 7) * 8;
      gload16(&Bt2[buf][(size_t)(wave * 64 + it * 256) * 8],
              Wob + (size_t)(n0 + row) * EMB + kb + col8);
    }
  };

  f32x4 acc[2][4] = {};
  stage(0, 0);
  drain_stage();
  __syncthreads();
  int cur = 0;
  for (int kt = 0; kt < 8; ++kt) {
    int nxt = cur ^ 1;
    if (kt < 7) stage(nxt, kt + 1);      // issue next-tile DMA before compute
    bf16x8 af[2][2], bfv[4][2];
#pragma unroll
    for (int m = 0; m < 2; ++m)
#pragma unroll
      for (int kk = 0; kk < 2; ++kk)
        af[m][kk] = *reinterpret_cast<const bf16x8*>(
            &At2[cur][(wr * 32 + m * 16 + fr) * 64 + kk * 32 + fq * 8]);
#pragma unroll
    for (int n = 0; n < 4; ++n)
#pragma unroll
      for (int kk = 0; kk < 2; ++kk)
        bfv[n][kk] = *reinterpret_cast<const bf16x8*>(
            &Bt2[cur][(wc * 64 + n * 16 + fr) * 64 + kk * 32 + fq * 8]);
#pragma unroll
    for (int m = 0; m < 2; ++m)
#pragma unroll
      for (int n = 0; n < 4; ++n) {
        acc[m][n] = __builtin_amdgcn_mfma_f32_16x16x32_bf16(af[m][0], bfv[n][0], acc[m][n], 0, 0, 0);
        acc[m][n] = __builtin_amdgcn_mfma_f32_16x16x32_bf16(af[m][1], bfv[n][1], acc[m][n], 0, 0, 0);
      }
    drain_stage();                       // next-tile DMA landed before publish
    __syncthreads();
    cur = nxt;
  }
  float bov[4];
#pragma unroll
  for (int n = 0; n < 4; ++n) bov[n] = bo[n0 + wc * 64 + n * 16 + fr];
#pragma unroll
  for (int m = 0; m < 2; ++m)
#pragma unroll
    for (int n = 0; n < 4; ++n) {
      int col = n0 + wc * 64 + n * 16 + fr;
#pragma unroll
      for (int r = 0; r < 4; ++r) {
        int row = m0 + wr * 32 + m * 16 + fq * 4 + r;
        out[(size_t)row * EMB + col] = acc[m][n][r] + bov[n];
      }
    }
}

extern "C" void kernel_launch(void* const* d_in, const int* in_sizes, int n_in,
                              void* d_out, int out_size, void* d_ws, size_t ws_size,
                              hipStream_t stream) {
  const float* x  = (const float*)d_in[0];
  const float* Wq = (const float*)d_in[1];
  const float* bq = (const float*)d_in[2];
  const float* Wk = (const float*)d_in[3];
  const float* bk = (const float*)d_in[4];
  const float* Wv = (const float*)d_in[5];
  const float* bv = (const float*)d_in[6];
  const float* Wo = (const float*)d_in[7];
  const float* bo = (const float*)d_in[8];
  float* out = (float*)d_out;

  char* ws = (char*)d_ws;
  u16* Vb       = (u16*)(ws);                                    // 8 MB
  u16* ao       = (u16*)(ws + (8u << 20));                       // 8 MB
  u16* Atm      = (u16*)(ws + (16u << 20));                      // 512 KB
  u16* Wvb      = (u16*)(ws + (16u << 20) + (512u << 10));       // 512 KB
  u16* Wob      = (u16*)(ws + (16u << 20) + (1024u << 10));      // 512 KB
  float* e_part = (float*)(ws + (16u << 20) + (1536u << 10));    // 256 KB
  float* cvec   = (float*)(ws + (16u << 20) + (1792u << 10));    // 2 KB
  u16* bvb      = (u16*)(ws + (16u << 20) + (1794u << 10));      // 1 KB
  float* econst = (float*)(ws + (16u << 20) + (1795u << 10));    // 4 B

  // 1) weight casts || fp32 atmat || cvec || econst+bvb
  prep1<<<777, 256, 0, stream>>>(Wq, Wk, Wv, Wo, bq, bk, bv,
                                 Wvb, Wob, Atm, bvb, cvec, econst);
  // 2) e partials + V (A self-staged from fp32 x), BK=64 2-phase dbuf
  gemm_ev2<<<512, 256, 0, stream>>>(x, Atm, Wvb, bv, cvec, e_part, Vb);
  // 3) window softmax + PV -> ao (bf16)
  window2<<<512, 256, 0, stream>>>(Vb, e_part, econst, bvb, ao);
  // 4) out = ao @ Wo^T + bo, BK=64 2-phase dbuf
  ogemm<<<512, 256, 0, stream>>>(ao, Wob, bo, out);
}